// Round 5
// baseline (1577.104 us; speedup 1.0000x reference)
//
#include <hip/hip_runtime.h>

// MultiHeadAttentionConvIndex — CSR gather, round 5.
// R4 finding: 5.5x write amplification (WRITE_SIZE 895 MB vs 166 MB logical)
// from scattered 8B stores dribbled across the j4 loop -> L2 lines evicted
// mid-row and RMW'd repeatedly. Fix: buffer row in LDS, then each wave writes
// its 64 rows as back-to-back dwordx4 bursts (full row per instruction).
//
// ws layout (main path):
//   vals : uint[E*52]   per-edge row = 48 uints (96 bf16 of p*vals) + 4 f32 p
//   agg  : float[N*96]  normalized aggregation (written by gather)
//   cntF : float[N]     in-degree as float
//   cnt_i: int[N]       histogram
//   offs : int[N]       CSR row starts
//   curs : int[N]       scatter cursors
// Fallback (ws too small): round-2 atomic path.

#define NEG 0.01f

__device__ __forceinline__ float lrelu(float v) { return v > 0.f ? v : NEG * v; }

__device__ __forceinline__ unsigned bfpack2(float a, float b) {
    unsigned ua = __float_as_uint(a); ua = (ua + 0x7fff + ((ua >> 16) & 1)) >> 16;
    unsigned ub = __float_as_uint(b); ub = (ub + 0x7fff + ((ub >> 16) & 1)) >> 16;
    return ua | (ub << 16);
}

__global__ void zero_kernel(float* __restrict__ p, long n) {
    long i = ((long)blockIdx.x * 256 + threadIdx.x) * 4;
    if (i + 3 < n) {
        *(float4*)(p + i) = make_float4(0.f, 0.f, 0.f, 0.f);
    } else {
        for (long k = i; k < n; ++k) p[k] = 0.f;
    }
}

__global__ void hist_kernel(const int* __restrict__ ei, int* __restrict__ cnt, int E) {
    int e = blockIdx.x * 256 + threadIdx.x;
    if (e < E) atomicAdd(&cnt[ei[E + e]], 1);
}

// Single-block exclusive scan over cnt[N] -> offs & cursors.
__global__ __launch_bounds__(1024)
void scan_kernel(const int* __restrict__ cnt, int* __restrict__ offs,
                 int* __restrict__ curs, int N) {
    __shared__ int ls[1024];
    int tid = threadIdx.x;
    int chunk = (N + 1023) >> 10;
    int lo = tid * chunk;
    int hi = lo + chunk; if (hi > N) hi = N; if (lo > N) lo = N;
    int s = 0;
    for (int i = lo; i < hi; ++i) s += cnt[i];
    ls[tid] = s;
    __syncthreads();
    for (int off = 1; off < 1024; off <<= 1) {
        int v = 0;
        if (tid >= off) v = ls[tid - off];
        __syncthreads();
        ls[tid] += v;
        __syncthreads();
    }
    int run = ls[tid] - s;
    for (int i = lo; i < hi; ++i) {
        offs[i] = run; curs[i] = run; run += cnt[i];
    }
}

// One thread per edge; row buffered in LDS; wave-cooperative burst writeout.
__global__ __launch_bounds__(256, 1)
void edge_csr_kernel(const float* __restrict__ x, const float* __restrict__ ea,
                     const int* __restrict__ ei,
                     const float* __restrict__ Wp, const float* __restrict__ bp,
                     const float* __restrict__ Wa, const float* __restrict__ ba,
                     const float* __restrict__ Wv, const float* __restrict__ bv,
                     unsigned* __restrict__ vals, int* __restrict__ curs, int E)
{
    __shared__ unsigned ls[256 * 52];          // 53 KB: one 208B row per thread

    int e = blockIdx.x * 256 + threadIdx.x;
    bool active = (e < E);
    int ec = active ? e : (E - 1);             // clamped for safe loads
    int src = ei[ec];
    int dst = ei[E + ec];

    float4 S[24];
#pragma unroll
    for (int j = 0; j < 24; ++j) S[j] = ((const float4*)bp)[j];

    const float* xrow = x + (long)src * 64;
    const float* erow = ea + (long)ec * 32;

#pragma unroll 1
    for (int kc = 0; kc < 6; ++kc) {
        const float* sp = (kc < 4) ? (xrow + kc * 16) : (erow + (kc - 4) * 16);
        const float* Wb = Wp + kc * 16 * 96;
#pragma unroll 1
        for (int i = 0; i < 4; ++i) {
            float4 cc = ((const float4*)sp)[i];
            const float* W0 = Wb + (4 * i + 0) * 96;
            const float* W1 = Wb + (4 * i + 1) * 96;
            const float* W2 = Wb + (4 * i + 2) * 96;
            const float* W3 = Wb + (4 * i + 3) * 96;
#pragma unroll
            for (int j = 0; j < 24; ++j) {
                float4 w0 = ((const float4*)W0)[j];
                float4 w1 = ((const float4*)W1)[j];
                float4 w2 = ((const float4*)W2)[j];
                float4 w3 = ((const float4*)W3)[j];
                S[j].x += cc.x * w0.x + cc.y * w1.x + cc.z * w2.x + cc.w * w3.x;
                S[j].y += cc.x * w0.y + cc.y * w1.y + cc.z * w2.y + cc.w * w3.y;
                S[j].z += cc.x * w0.z + cc.y * w1.z + cc.z * w2.z + cc.w * w3.z;
                S[j].w += cc.x * w0.w + cc.y * w1.w + cc.z * w2.w + cc.w * w3.w;
            }
        }
    }
#pragma unroll
    for (int j = 0; j < 24; ++j) {
        S[j].x = lrelu(S[j].x); S[j].y = lrelu(S[j].y);
        S[j].z = lrelu(S[j].z); S[j].w = lrelu(S[j].w);
    }

    float l0 = ba[0], l1 = ba[1], l2 = ba[2], l3 = ba[3];
#pragma unroll
    for (int j = 0; j < 24; ++j) {
        float4 m = S[j];
        float4 w0 = ((const float4*)(Wa + (4 * j + 0) * 4))[0];
        float4 w1 = ((const float4*)(Wa + (4 * j + 1) * 4))[0];
        float4 w2 = ((const float4*)(Wa + (4 * j + 2) * 4))[0];
        float4 w3 = ((const float4*)(Wa + (4 * j + 3) * 4))[0];
        l0 += m.x * w0.x + m.y * w1.x + m.z * w2.x + m.w * w3.x;
        l1 += m.x * w0.y + m.y * w1.y + m.z * w2.y + m.w * w3.y;
        l2 += m.x * w0.z + m.y * w1.z + m.z * w2.z + m.w * w3.z;
        l3 += m.x * w0.w + m.y * w1.w + m.z * w2.w + m.w * w3.w;
    }
    float p0 = __expf(l0), p1 = __expf(l1), p2 = __expf(l2), p3 = __expf(l3);

    int pos = 0;
    if (active) pos = atomicAdd(&curs[dst], 1);

    unsigned* lrow = ls + threadIdx.x * 52;
#pragma unroll 1
    for (int j4 = 0; j4 < 24; ++j4) {
        float4 acc = ((const float4*)bv)[j4];
        const float* Wc = Wv + 4 * j4;
#pragma unroll
        for (int j = 0; j < 24; ++j) {
            float4 m = S[j];
            float4 w0 = ((const float4*)(Wc + (4 * j + 0) * 96))[0];
            float4 w1 = ((const float4*)(Wc + (4 * j + 1) * 96))[0];
            float4 w2 = ((const float4*)(Wc + (4 * j + 2) * 96))[0];
            float4 w3 = ((const float4*)(Wc + (4 * j + 3) * 96))[0];
            acc.x += m.x * w0.x + m.y * w1.x + m.z * w2.x + m.w * w3.x;
            acc.y += m.x * w0.y + m.y * w1.y + m.z * w2.y + m.w * w3.y;
            acc.z += m.x * w0.z + m.y * w1.z + m.z * w2.z + m.w * w3.z;
            acc.w += m.x * w0.w + m.y * w1.w + m.z * w2.w + m.w * w3.w;
        }
        float ph = (j4 < 6) ? p0 : (j4 < 12) ? p1 : (j4 < 18) ? p2 : p3;
        ((uint2*)lrow)[j4] = make_uint2(bfpack2(ph * acc.x, ph * acc.y),
                                        bfpack2(ph * acc.z, ph * acc.w));
    }
    ((uint4*)lrow)[12] = make_uint4(__float_as_uint(p0), __float_as_uint(p1),
                                    __float_as_uint(p2), __float_as_uint(p3));

    __syncthreads();

    // Wave-cooperative writeout: each wave writes its own 64 rows as one
    // dwordx4 burst (13 lanes x 16 B = 208 B) per row -> lines written fully
    // within a few cycles -> single writeback per line.
    int wv = threadIdx.x >> 6;
    int lane = threadIdx.x & 63;
    const uint4* lsrow0 = (const uint4*)(ls + (wv * 64) * 52);
#pragma unroll 1
    for (int i = 0; i < 64; ++i) {
        int pos_i = __shfl(pos, i, 64);
        int act_i = __shfl((int)active, i, 64);
        if (act_i && lane < 13) {
            ((uint4*)(vals + (long)pos_i * 52))[lane] =
                *(const uint4*)((const unsigned*)lsrow0 + i * 52 + lane * 4);
        }
    }
}

// One wave per node: sum its contiguous CSR rows, normalize, write agg+count.
// Denominator shfl executed by ALL 64 lanes (R3 NaN bug).
__global__ __launch_bounds__(256, 4)
void gather_kernel(const unsigned* __restrict__ vals, const int* __restrict__ offs,
                   const int* __restrict__ cnt, float* __restrict__ agg,
                   float* __restrict__ cntF, int N)
{
    int node = blockIdx.x * 4 + (threadIdx.x >> 6);
    int lane = threadIdx.x & 63;
    if (node >= N) return;           // wave-uniform exit
    int start = offs[node];
    int deg = cnt[node];

    float s0 = 0.f, s1 = 0.f, sp = 0.f;
    if (lane < 52) {
        const unsigned* p = vals + (long)start * 52 + lane;
        for (int r = 0; r < deg; ++r, p += 52) {
            unsigned v = *p;
            if (lane < 48) {
                s0 += __uint_as_float(v << 16);
                s1 += __uint_as_float(v & 0xffff0000u);
            } else {
                sp += __uint_as_float(v);
            }
        }
    }
    int srcl = 48 + ((lane < 48) ? (lane / 12) : 0);
    float d = __shfl(sp, srcl, 64);

    if (lane < 48) {
        float2 o;
        if (deg > 0) { o.x = s0 / d; o.y = s1 / d; }
        else         { o.x = 0.f;    o.y = 0.f; }
        *(float2*)(agg + (long)node * 96 + 2 * lane) = o;
    } else if (lane == 48) {
        cntF[node] = (float)deg;
    }
}

// out = leaky_relu([x | agg | count] @ W_out + b_out)
__global__ __launch_bounds__(256, 4)
void node_kernel(const float* __restrict__ x, const float* __restrict__ aggW,
                 const float* __restrict__ cntF,
                 const float* __restrict__ Wo, const float* __restrict__ bo,
                 float* __restrict__ out, int N)
{
    __shared__ float s_in[161][64];
    int n0 = blockIdx.x * 64;
    int j0 = blockIdx.y * 64;

    for (int p = threadIdx.x; p < 161 * 64; p += 256) {
        int k = p >> 6, nl = p & 63;
        int n = n0 + nl;
        float v = 0.f;
        if (n < N) {
            if (k < 64)       v = x[(long)n * 64 + k];
            else if (k < 160) v = aggW[(long)n * 96 + (k - 64)];
            else              v = cntF[n];
        }
        s_in[k][nl] = v;
    }
    __syncthreads();

    int tj = threadIdx.x & 15;
    int tn = threadIdx.x >> 4;
    float acc[4][4];
#pragma unroll
    for (int i = 0; i < 4; ++i)
#pragma unroll
        for (int c = 0; c < 4; ++c) acc[i][c] = 0.f;

    const float* Wcol = Wo + j0 + tj * 4;
    for (int k = 0; k < 161; ++k) {
        float4 w  = *(const float4*)(Wcol + (long)k * 128);
        float4 iv = *(const float4*)&s_in[k][tn * 4];
        acc[0][0] += iv.x * w.x; acc[0][1] += iv.x * w.y; acc[0][2] += iv.x * w.z; acc[0][3] += iv.x * w.w;
        acc[1][0] += iv.y * w.x; acc[1][1] += iv.y * w.y; acc[1][2] += iv.y * w.z; acc[1][3] += iv.y * w.w;
        acc[2][0] += iv.z * w.x; acc[2][1] += iv.z * w.y; acc[2][2] += iv.z * w.z; acc[2][3] += iv.z * w.w;
        acc[3][0] += iv.w * w.x; acc[3][1] += iv.w * w.y; acc[3][2] += iv.w * w.z; acc[3][3] += iv.w * w.w;
    }
    float4 b = *(const float4*)(bo + j0 + tj * 4);
#pragma unroll
    for (int i = 0; i < 4; ++i) {
        int n = n0 + tn * 4 + i;
        if (n < N) {
            float4 o;
            o.x = lrelu(acc[i][0] + b.x);
            o.y = lrelu(acc[i][1] + b.y);
            o.z = lrelu(acc[i][2] + b.z);
            o.w = lrelu(acc[i][3] + b.w);
            *(float4*)(out + (long)n * 128 + j0 + tj * 4) = o;
        }
    }
}

// ---------------- fallback (round-2 atomic path, used if ws too small) -----
__global__ __launch_bounds__(256, 1)
void edge_atm_kernel(const float* __restrict__ x, const float* __restrict__ ea,
                     const int* __restrict__ ei,
                     const float* __restrict__ Wp, const float* __restrict__ bp,
                     const float* __restrict__ Wa, const float* __restrict__ ba,
                     const float* __restrict__ Wv, const float* __restrict__ bv,
                     float* __restrict__ aggW, float* __restrict__ denomW,
                     float* __restrict__ cntW, int E)
{
    int e = blockIdx.x * 256 + threadIdx.x;
    if (e >= E) return;
    int src = ei[e];
    int dst = ei[E + e];
    float4 S[24];
#pragma unroll
    for (int j = 0; j < 24; ++j) S[j] = ((const float4*)bp)[j];
    const float* xrow = x + (long)src * 64;
    const float* erow = ea + (long)e * 32;
#pragma unroll 1
    for (int kc = 0; kc < 6; ++kc) {
        const float* sp = (kc < 4) ? (xrow + kc * 16) : (erow + (kc - 4) * 16);
        const float* Wb = Wp + kc * 16 * 96;
#pragma unroll 1
        for (int i = 0; i < 4; ++i) {
            float4 cc = ((const float4*)sp)[i];
#pragma unroll
            for (int j = 0; j < 24; ++j) {
                float4 w0 = ((const float4*)(Wb + (4 * i + 0) * 96))[j];
                float4 w1 = ((const float4*)(Wb + (4 * i + 1) * 96))[j];
                float4 w2 = ((const float4*)(Wb + (4 * i + 2) * 96))[j];
                float4 w3 = ((const float4*)(Wb + (4 * i + 3) * 96))[j];
                S[j].x += cc.x * w0.x + cc.y * w1.x + cc.z * w2.x + cc.w * w3.x;
                S[j].y += cc.x * w0.y + cc.y * w1.y + cc.z * w2.y + cc.w * w3.y;
                S[j].z += cc.x * w0.z + cc.y * w1.z + cc.z * w2.z + cc.w * w3.z;
                S[j].w += cc.x * w0.w + cc.y * w1.w + cc.z * w2.w + cc.w * w3.w;
            }
        }
    }
#pragma unroll
    for (int j = 0; j < 24; ++j) {
        S[j].x = lrelu(S[j].x); S[j].y = lrelu(S[j].y);
        S[j].z = lrelu(S[j].z); S[j].w = lrelu(S[j].w);
    }
    float l0 = ba[0], l1 = ba[1], l2 = ba[2], l3 = ba[3];
#pragma unroll
    for (int j = 0; j < 24; ++j) {
        float4 m = S[j];
        float4 w0 = ((const float4*)(Wa + (4 * j + 0) * 4))[0];
        float4 w1 = ((const float4*)(Wa + (4 * j + 1) * 4))[0];
        float4 w2 = ((const float4*)(Wa + (4 * j + 2) * 4))[0];
        float4 w3 = ((const float4*)(Wa + (4 * j + 3) * 4))[0];
        l0 += m.x * w0.x + m.y * w1.x + m.z * w2.x + m.w * w3.x;
        l1 += m.x * w0.y + m.y * w1.y + m.z * w2.y + m.w * w3.y;
        l2 += m.x * w0.z + m.y * w1.z + m.z * w2.z + m.w * w3.z;
        l3 += m.x * w0.w + m.y * w1.w + m.z * w2.w + m.w * w3.w;
    }
    float p0 = __expf(l0), p1 = __expf(l1), p2 = __expf(l2), p3 = __expf(l3);
    float* aggp = aggW + (long)dst * 96;
#pragma unroll 1
    for (int j4 = 0; j4 < 24; ++j4) {
        float4 acc = ((const float4*)bv)[j4];
        const float* Wc = Wv + 4 * j4;
#pragma unroll
        for (int j = 0; j < 24; ++j) {
            float4 m = S[j];
            float4 w0 = ((const float4*)(Wc + (4 * j + 0) * 96))[0];
            float4 w1 = ((const float4*)(Wc + (4 * j + 1) * 96))[0];
            float4 w2 = ((const float4*)(Wc + (4 * j + 2) * 96))[0];
            float4 w3 = ((const float4*)(Wc + (4 * j + 3) * 96))[0];
            acc.x += m.x * w0.x + m.y * w1.x + m.z * w2.x + m.w * w3.x;
            acc.y += m.x * w0.y + m.y * w1.y + m.z * w2.y + m.w * w3.y;
            acc.z += m.x * w0.z + m.y * w1.z + m.z * w2.z + m.w * w3.z;
            acc.w += m.x * w0.w + m.y * w1.w + m.z * w2.w + m.w * w3.w;
        }
        float ph = (j4 < 6) ? p0 : (j4 < 12) ? p1 : (j4 < 18) ? p2 : p3;
        unsafeAtomicAdd(aggp + 4 * j4 + 0, ph * acc.x);
        unsafeAtomicAdd(aggp + 4 * j4 + 1, ph * acc.y);
        unsafeAtomicAdd(aggp + 4 * j4 + 2, ph * acc.z);
        unsafeAtomicAdd(aggp + 4 * j4 + 3, ph * acc.w);
    }
    float* dn = denomW + (long)dst * 4;
    unsafeAtomicAdd(dn + 0, p0);
    unsafeAtomicAdd(dn + 1, p1);
    unsafeAtomicAdd(dn + 2, p2);
    unsafeAtomicAdd(dn + 3, p3);
    unsafeAtomicAdd(cntW + dst, 1.0f);
}

__global__ __launch_bounds__(256, 4)
void node_atm_kernel(const float* __restrict__ x, const float* __restrict__ aggW,
                     const float* __restrict__ denomW, const float* __restrict__ cntW,
                     const float* __restrict__ Wo, const float* __restrict__ bo,
                     float* __restrict__ out, int N)
{
    __shared__ float s_in[161][64];
    int n0 = blockIdx.x * 64;
    int j0 = blockIdx.y * 64;
    for (int p = threadIdx.x; p < 161 * 64; p += 256) {
        int k = p >> 6, nl = p & 63;
        int n = n0 + nl;
        float v = 0.f;
        if (n < N) {
            if (k < 64) v = x[(long)n * 64 + k];
            else if (k < 160) {
                int kk = k - 64;
                float d = denomW[n * 4 + (kk / 24)];
                v = d > 0.f ? aggW[(long)n * 96 + kk] / d : 0.f;
            } else v = cntW[n];
        }
        s_in[k][nl] = v;
    }
    __syncthreads();
    int tj = threadIdx.x & 15;
    int tn = threadIdx.x >> 4;
    float acc[4][4];
#pragma unroll
    for (int i = 0; i < 4; ++i)
#pragma unroll
        for (int c = 0; c < 4; ++c) acc[i][c] = 0.f;
    const float* Wcol = Wo + j0 + tj * 4;
    for (int k = 0; k < 161; ++k) {
        float4 w  = *(const float4*)(Wcol + (long)k * 128);
        float4 iv = *(const float4*)&s_in[k][tn * 4];
        acc[0][0] += iv.x * w.x; acc[0][1] += iv.x * w.y; acc[0][2] += iv.x * w.z; acc[0][3] += iv.x * w.w;
        acc[1][0] += iv.y * w.x; acc[1][1] += iv.y * w.y; acc[1][2] += iv.y * w.z; acc[1][3] += iv.y * w.w;
        acc[2][0] += iv.z * w.x; acc[2][1] += iv.z * w.y; acc[2][2] += iv.z * w.z; acc[2][3] += iv.z * w.w;
        acc[3][0] += iv.w * w.x; acc[3][1] += iv.w * w.y; acc[3][2] += iv.w * w.z; acc[3][3] += iv.w * w.w;
    }
    float4 b = *(const float4*)(bo + j0 + tj * 4);
#pragma unroll
    for (int i = 0; i < 4; ++i) {
        int n = n0 + tn * 4 + i;
        if (n < N) {
            float4 o;
            o.x = lrelu(acc[i][0] + b.x);
            o.y = lrelu(acc[i][1] + b.y);
            o.z = lrelu(acc[i][2] + b.z);
            o.w = lrelu(acc[i][3] + b.w);
            *(float4*)(out + (long)n * 128 + j0 + tj * 4) = o;
        }
    }
}

extern "C" void kernel_launch(void* const* d_in, const int* in_sizes, int n_in,
                              void* d_out, int out_size, void* d_ws, size_t ws_size,
                              hipStream_t stream)
{
    const float* x  = (const float*)d_in[0];
    const float* ea = (const float*)d_in[1];
    const int*   ei = (const int*)d_in[2];
    const float* Wp = (const float*)d_in[3];
    const float* bp = (const float*)d_in[4];
    const float* Wa = (const float*)d_in[5];
    const float* ba = (const float*)d_in[6];
    const float* Wv = (const float*)d_in[7];
    const float* bv = (const float*)d_in[8];
    const float* Wo = (const float*)d_in[9];
    const float* bo = (const float*)d_in[10];
    float* out = (float*)d_out;

    int N = in_sizes[0] / 64;
    int E = in_sizes[2] / 2;

    size_t need = (size_t)E * 52 * 4 + (size_t)N * 96 * 4 + (size_t)N * 4 * 4;

    if (ws_size >= need) {
        unsigned* vals = (unsigned*)d_ws;
        float* aggW = (float*)(vals + (long)E * 52);
        float* cntF = aggW + (long)N * 96;
        int*   cnti = (int*)(cntF + N);
        int*   offs = cnti + N;
        int*   curs = offs + N;

        hipMemsetAsync(cnti, 0, (size_t)N * sizeof(int), stream);
        hist_kernel<<<(E + 255) / 256, 256, 0, stream>>>(ei, cnti, E);
        scan_kernel<<<1, 1024, 0, stream>>>(cnti, offs, curs, N);
        edge_csr_kernel<<<(E + 255) / 256, 256, 0, stream>>>(
            x, ea, ei, Wp, bp, Wa, ba, Wv, bv, vals, curs, E);
        gather_kernel<<<(N + 3) / 4, 256, 0, stream>>>(vals, offs, cnti, aggW, cntF, N);
        dim3 ng((N + 63) / 64, 2);
        node_kernel<<<ng, 256, 0, stream>>>(x, aggW, cntF, Wo, bo, out, N);
    } else {
        float* aggW   = (float*)d_ws;
        float* denomW = aggW + (long)N * 96;
        float* cntW   = denomW + (long)N * 4;
        long zn = (long)N * 101;
        int  zb = (int)(((zn + 3) / 4 + 255) / 256);
        zero_kernel<<<zb, 256, 0, stream>>>(aggW, zn);
        edge_atm_kernel<<<(E + 255) / 256, 256, 0, stream>>>(
            x, ea, ei, Wp, bp, Wa, ba, Wv, bv, aggW, denomW, cntW, E);
        dim3 ng((N + 63) / 64, 2);
        node_atm_kernel<<<ng, 256, 0, stream>>>(x, aggW, denomW, cntW, Wo, bo, out, N);
    }
}

// Round 6
// 1216.050 us; speedup vs baseline: 1.2969x; 1.2969x over previous
//
#include <hip/hip_runtime.h>

// MultiHeadAttentionConvIndex — round 6: algebraic restructure.
// R5 lesson: kernel is issue/latency-bound, not write-BW-bound. So cut FLOPs:
//  (a) U = x@Wp[0:64]+bp per NODE (dense GEMM), edge adds only ea@Wp[64:96].
//  (b) Sum-alpha=1 per head => agg = (sum_e p_h*msg / sum_e p_h)@Wv + bv:
//      the 9216-FMA vals GEMM moves from per-edge to per-node (8x fewer).
// Edge row: 48 uints (96 bf16 msg) + 4 f32 p = 208 B, burst-stored from regs.
//
// ws: vals[E*52 u32] | U/agg alias [N*96 f32] | cntF[N] | cnti[N] offs[N] curs[N]

#define NEG 0.01f

__device__ __forceinline__ float lrelu(float v) { return v > 0.f ? v : NEG * v; }

__device__ __forceinline__ unsigned bfpack2(float a, float b) {
    unsigned ua = __float_as_uint(a); ua = (ua + 0x7fff + ((ua >> 16) & 1)) >> 16;
    unsigned ub = __float_as_uint(b); ub = (ub + 0x7fff + ((ub >> 16) & 1)) >> 16;
    return ua | (ub << 16);
}

__global__ void zero_kernel(float* __restrict__ p, long n) {
    long i = ((long)blockIdx.x * 256 + threadIdx.x) * 4;
    if (i + 3 < n) {
        *(float4*)(p + i) = make_float4(0.f, 0.f, 0.f, 0.f);
    } else {
        for (long k = i; k < n; ++k) p[k] = 0.f;
    }
}

__global__ void hist_kernel(const int* __restrict__ ei, int* __restrict__ cnt, int E) {
    int e = blockIdx.x * 256 + threadIdx.x;
    if (e < E) atomicAdd(&cnt[ei[E + e]], 1);
}

__global__ __launch_bounds__(1024)
void scan_kernel(const int* __restrict__ cnt, int* __restrict__ offs,
                 int* __restrict__ curs, int N) {
    __shared__ int ls[1024];
    int tid = threadIdx.x;
    int chunk = (N + 1023) >> 10;
    int lo = tid * chunk;
    int hi = lo + chunk; if (hi > N) hi = N; if (lo > N) lo = N;
    int s = 0;
    for (int i = lo; i < hi; ++i) s += cnt[i];
    ls[tid] = s;
    __syncthreads();
    for (int off = 1; off < 1024; off <<= 1) {
        int v = 0;
        if (tid >= off) v = ls[tid - off];
        __syncthreads();
        ls[tid] += v;
        __syncthreads();
    }
    int run = ls[tid] - s;
    for (int i = lo; i < hi; ++i) {
        offs[i] = run; curs[i] = run; run += cnt[i];
    }
}

// U = x @ Wp[0:64,:] + bp   ([N,64]@[64,96], dense)
// 64 nodes/block; thread = (node, 24-col group).
__global__ __launch_bounds__(256, 4)
void pre_kernel(const float* __restrict__ x, const float* __restrict__ Wp,
                const float* __restrict__ bp, float* __restrict__ U, int N)
{
    __shared__ float xs[64][65];
    int n0 = blockIdx.x * 64;
    for (int p = threadIdx.x; p < 64 * 16; p += 256) {
        int row = p >> 4, f4 = p & 15;
        int n = n0 + row;
        float4 v = make_float4(0.f, 0.f, 0.f, 0.f);
        if (n < N) v = ((const float4*)(x + (long)n * 64))[f4];
        xs[row][f4 * 4 + 0] = v.x; xs[row][f4 * 4 + 1] = v.y;
        xs[row][f4 * 4 + 2] = v.z; xs[row][f4 * 4 + 3] = v.w;
    }
    __syncthreads();

    int node = threadIdx.x >> 2;
    int cg = threadIdx.x & 3;           // 4 col-groups of 24
    float4 acc[6];
#pragma unroll
    for (int c = 0; c < 6; ++c) acc[c] = ((const float4*)(bp + cg * 24))[c];
    for (int k = 0; k < 64; ++k) {
        float xv = xs[node][k];
        const float* wr = Wp + k * 96 + cg * 24;
#pragma unroll
        for (int c = 0; c < 6; ++c) {
            float4 w = ((const float4*)wr)[c];
            acc[c].x += xv * w.x; acc[c].y += xv * w.y;
            acc[c].z += xv * w.z; acc[c].w += xv * w.w;
        }
    }
    int n = n0 + node;
    if (n < N) {
#pragma unroll
        for (int c = 0; c < 6; ++c)
            ((float4*)(U + (long)n * 96 + cg * 24))[c] = acc[c];
    }
}

// One thread per edge: msg = lrelu(U[src] + ea@Wp2); p = exp(msg@Wa+ba);
// burst-store row {bf16 msg x96, f32 p x4} at CSR slot.
__global__ __launch_bounds__(256, 1)
void edge_msg_kernel(const float* __restrict__ U, const float* __restrict__ ea,
                     const int* __restrict__ ei,
                     const float* __restrict__ Wp,
                     const float* __restrict__ Wa, const float* __restrict__ ba,
                     unsigned* __restrict__ vals, int* __restrict__ curs, int E)
{
    int e = blockIdx.x * 256 + threadIdx.x;
    bool active = (e < E);
    int ec = active ? e : (E - 1);
    int src = ei[ec];
    int dst = ei[E + ec];

    float4 S[24];
    const float4* Urow = (const float4*)(U + (long)src * 96);
#pragma unroll
    for (int j = 0; j < 24; ++j) S[j] = Urow[j];

    const float* erow = ea + (long)ec * 32;
    const float* Wp2 = Wp + 64 * 96;

#pragma unroll 1
    for (int kc = 0; kc < 2; ++kc) {          // 2 chunks of 16 edge feats
#pragma unroll 1
        for (int i = 0; i < 4; ++i) {
            float4 cc = ((const float4*)(erow + kc * 16))[i];
            const float* W0 = Wp2 + (kc * 16 + 4 * i + 0) * 96;
            const float* W1 = Wp2 + (kc * 16 + 4 * i + 1) * 96;
            const float* W2 = Wp2 + (kc * 16 + 4 * i + 2) * 96;
            const float* W3 = Wp2 + (kc * 16 + 4 * i + 3) * 96;
#pragma unroll
            for (int j = 0; j < 24; ++j) {
                float4 w0 = ((const float4*)W0)[j];
                float4 w1 = ((const float4*)W1)[j];
                float4 w2 = ((const float4*)W2)[j];
                float4 w3 = ((const float4*)W3)[j];
                S[j].x += cc.x * w0.x + cc.y * w1.x + cc.z * w2.x + cc.w * w3.x;
                S[j].y += cc.x * w0.y + cc.y * w1.y + cc.z * w2.y + cc.w * w3.y;
                S[j].z += cc.x * w0.z + cc.y * w1.z + cc.z * w2.z + cc.w * w3.z;
                S[j].w += cc.x * w0.w + cc.y * w1.w + cc.z * w2.w + cc.w * w3.w;
            }
        }
    }
#pragma unroll
    for (int j = 0; j < 24; ++j) {
        S[j].x = lrelu(S[j].x); S[j].y = lrelu(S[j].y);
        S[j].z = lrelu(S[j].z); S[j].w = lrelu(S[j].w);
    }

    float l0 = ba[0], l1 = ba[1], l2 = ba[2], l3 = ba[3];
#pragma unroll
    for (int j = 0; j < 24; ++j) {
        float4 m = S[j];
        float4 w0 = ((const float4*)(Wa + (4 * j + 0) * 4))[0];
        float4 w1 = ((const float4*)(Wa + (4 * j + 1) * 4))[0];
        float4 w2 = ((const float4*)(Wa + (4 * j + 2) * 4))[0];
        float4 w3 = ((const float4*)(Wa + (4 * j + 3) * 4))[0];
        l0 += m.x * w0.x + m.y * w1.x + m.z * w2.x + m.w * w3.x;
        l1 += m.x * w0.y + m.y * w1.y + m.z * w2.y + m.w * w3.y;
        l2 += m.x * w0.z + m.y * w1.z + m.z * w2.z + m.w * w3.z;
        l3 += m.x * w0.w + m.y * w1.w + m.z * w2.w + m.w * w3.w;
    }
    float p0 = __expf(l0), p1 = __expf(l1), p2 = __expf(l2), p3 = __expf(l3);

    if (active) {
        int pos = atomicAdd(&curs[dst], 1);
        unsigned* row = vals + (long)pos * 52;
#pragma unroll
        for (int j2 = 0; j2 < 12; ++j2) {       // 13 x dwordx4 burst
            uint4 u;
            u.x = bfpack2(S[2 * j2].x,     S[2 * j2].y);
            u.y = bfpack2(S[2 * j2].z,     S[2 * j2].w);
            u.z = bfpack2(S[2 * j2 + 1].x, S[2 * j2 + 1].y);
            u.w = bfpack2(S[2 * j2 + 1].z, S[2 * j2 + 1].w);
            ((uint4*)row)[j2] = u;
        }
        ((uint4*)row)[12] = make_uint4(__float_as_uint(p0), __float_as_uint(p1),
                                       __float_as_uint(p2), __float_as_uint(p3));
    }
}

// One wave per node: T_h = sum_e p_h*msg_e; then agg = (T_h/sum p_h)@Wv + bv.
// Shfl sources 48..51 are active inside the lane<52 scope (R3 lesson).
__global__ __launch_bounds__(256, 4)
void gather_kernel(const unsigned* __restrict__ vals, const int* __restrict__ offs,
                   const int* __restrict__ cnt,
                   const float* __restrict__ Wv, const float* __restrict__ bv,
                   float* __restrict__ agg, float* __restrict__ cntF, int N)
{
    __shared__ float Tls[4][4][96];            // [wave][head][k], 6 KB
    int wv = threadIdx.x >> 6;
    int lane = threadIdx.x & 63;
    int node = blockIdx.x * 4 + wv;
    if (node >= N) return;                     // wave-uniform exit
    int start = offs[node];
    int deg = cnt[node];

    float s0[4] = {0.f, 0.f, 0.f, 0.f};
    float s1[4] = {0.f, 0.f, 0.f, 0.f};
    float d0 = 0.f, d1 = 0.f, d2 = 0.f, d3 = 0.f;
    if (lane < 52) {
        const unsigned* p = vals + (long)start * 52 + lane;
        for (int r = 0; r < deg; ++r, p += 52) {
            unsigned v = *p;
            float vf = __uint_as_float(v);
            float q0 = __shfl(vf, 48, 64);     // sources 48..51 active here
            float q1 = __shfl(vf, 49, 64);
            float q2 = __shfl(vf, 50, 64);
            float q3 = __shfl(vf, 51, 64);
            if (lane < 48) {
                float m0 = __uint_as_float(v << 16);
                float m1 = __uint_as_float(v & 0xffff0000u);
                s0[0] += q0 * m0; s1[0] += q0 * m1;
                s0[1] += q1 * m0; s1[1] += q1 * m1;
                s0[2] += q2 * m0; s1[2] += q2 * m1;
                s0[3] += q3 * m0; s1[3] += q3 * m1;
                d0 += q0; d1 += q1; d2 += q2; d3 += q3;
            }
        }
    }
    if (lane < 48) {
        float r0 = (deg > 0) ? 1.f / d0 : 0.f;
        float r1 = (deg > 0) ? 1.f / d1 : 0.f;
        float r2 = (deg > 0) ? 1.f / d2 : 0.f;
        float r3 = (deg > 0) ? 1.f / d3 : 0.f;
        Tls[wv][0][2 * lane] = s0[0] * r0; Tls[wv][0][2 * lane + 1] = s1[0] * r0;
        Tls[wv][1][2 * lane] = s0[1] * r1; Tls[wv][1][2 * lane + 1] = s1[1] * r1;
        Tls[wv][2][2 * lane] = s0[2] * r2; Tls[wv][2][2 * lane + 1] = s1[2] * r2;
        Tls[wv][3][2 * lane] = s0[3] * r3; Tls[wv][3][2 * lane + 1] = s1[3] * r3;
    }
    // Same-wave LDS producer/consumer: lgkmcnt wait is compiler-inserted;
    // no block barrier needed (each wave reads only its own Tls[wv]).
    if (lane < 48) {
        int j = 2 * lane;                      // output cols j, j+1
        int h = lane / 12;                     // head (pairs never straddle)
        float a0 = bv[j], a1 = bv[j + 1];
        const float* Th = &Tls[wv][h][0];
        const float* wp = Wv + j;
#pragma unroll 4
        for (int k = 0; k < 96; ++k) {
            float t = Th[k];
            float2 w = *(const float2*)(wp + (long)k * 96);
            a0 += t * w.x; a1 += t * w.y;
        }
        float2 o = (deg > 0) ? make_float2(a0, a1) : make_float2(0.f, 0.f);
        *(float2*)(agg + (long)node * 96 + j) = o;
    } else if (lane == 48) {
        cntF[node] = (float)deg;
    }
}

// out = leaky_relu([x | agg | count] @ W_out + b_out)
__global__ __launch_bounds__(256, 4)
void node_kernel(const float* __restrict__ x, const float* __restrict__ aggW,
                 const float* __restrict__ cntF,
                 const float* __restrict__ Wo, const float* __restrict__ bo,
                 float* __restrict__ out, int N)
{
    __shared__ float s_in[161][64];
    int n0 = blockIdx.x * 64;
    int j0 = blockIdx.y * 64;

    for (int p = threadIdx.x; p < 161 * 64; p += 256) {
        int k = p >> 6, nl = p & 63;
        int n = n0 + nl;
        float v = 0.f;
        if (n < N) {
            if (k < 64)       v = x[(long)n * 64 + k];
            else if (k < 160) v = aggW[(long)n * 96 + (k - 64)];
            else              v = cntF[n];
        }
        s_in[k][nl] = v;
    }
    __syncthreads();

    int tj = threadIdx.x & 15;
    int tn = threadIdx.x >> 4;
    float acc[4][4];
#pragma unroll
    for (int i = 0; i < 4; ++i)
#pragma unroll
        for (int c = 0; c < 4; ++c) acc[i][c] = 0.f;

    const float* Wcol = Wo + j0 + tj * 4;
    for (int k = 0; k < 161; ++k) {
        float4 w  = *(const float4*)(Wcol + (long)k * 128);
        float4 iv = *(const float4*)&s_in[k][tn * 4];
        acc[0][0] += iv.x * w.x; acc[0][1] += iv.x * w.y; acc[0][2] += iv.x * w.z; acc[0][3] += iv.x * w.w;
        acc[1][0] += iv.y * w.x; acc[1][1] += iv.y * w.y; acc[1][2] += iv.y * w.z; acc[1][3] += iv.y * w.w;
        acc[2][0] += iv.z * w.x; acc[2][1] += iv.z * w.y; acc[2][2] += iv.z * w.z; acc[2][3] += iv.z * w.w;
        acc[3][0] += iv.w * w.x; acc[3][1] += iv.w * w.y; acc[3][2] += iv.w * w.z; acc[3][3] += iv.w * w.w;
    }
    float4 b = *(const float4*)(bo + j0 + tj * 4);
#pragma unroll
    for (int i = 0; i < 4; ++i) {
        int n = n0 + tn * 4 + i;
        if (n < N) {
            float4 o;
            o.x = lrelu(acc[i][0] + b.x);
            o.y = lrelu(acc[i][1] + b.y);
            o.z = lrelu(acc[i][2] + b.z);
            o.w = lrelu(acc[i][3] + b.w);
            *(float4*)(out + (long)n * 128 + j0 + tj * 4) = o;
        }
    }
}

// ---------------- fallback (round-2 atomic path, used if ws too small) -----
__global__ __launch_bounds__(256, 1)
void edge_atm_kernel(const float* __restrict__ x, const float* __restrict__ ea,
                     const int* __restrict__ ei,
                     const float* __restrict__ Wp, const float* __restrict__ bp,
                     const float* __restrict__ Wa, const float* __restrict__ ba,
                     const float* __restrict__ Wv, const float* __restrict__ bv,
                     float* __restrict__ aggW, float* __restrict__ denomW,
                     float* __restrict__ cntW, int E)
{
    int e = blockIdx.x * 256 + threadIdx.x;
    if (e >= E) return;
    int src = ei[e];
    int dst = ei[E + e];
    float4 S[24];
#pragma unroll
    for (int j = 0; j < 24; ++j) S[j] = ((const float4*)bp)[j];
    const float* xrow = x + (long)src * 64;
    const float* erow = ea + (long)e * 32;
#pragma unroll 1
    for (int kc = 0; kc < 6; ++kc) {
        const float* sp = (kc < 4) ? (xrow + kc * 16) : (erow + (kc - 4) * 16);
        const float* Wb = Wp + kc * 16 * 96;
#pragma unroll 1
        for (int i = 0; i < 4; ++i) {
            float4 cc = ((const float4*)sp)[i];
#pragma unroll
            for (int j = 0; j < 24; ++j) {
                float4 w0 = ((const float4*)(Wb + (4 * i + 0) * 96))[j];
                float4 w1 = ((const float4*)(Wb + (4 * i + 1) * 96))[j];
                float4 w2 = ((const float4*)(Wb + (4 * i + 2) * 96))[j];
                float4 w3 = ((const float4*)(Wb + (4 * i + 3) * 96))[j];
                S[j].x += cc.x * w0.x + cc.y * w1.x + cc.z * w2.x + cc.w * w3.x;
                S[j].y += cc.x * w0.y + cc.y * w1.y + cc.z * w2.y + cc.w * w3.y;
                S[j].z += cc.x * w0.z + cc.y * w1.z + cc.z * w2.z + cc.w * w3.z;
                S[j].w += cc.x * w0.w + cc.y * w1.w + cc.z * w2.w + cc.w * w3.w;
            }
        }
    }
#pragma unroll
    for (int j = 0; j < 24; ++j) {
        S[j].x = lrelu(S[j].x); S[j].y = lrelu(S[j].y);
        S[j].z = lrelu(S[j].z); S[j].w = lrelu(S[j].w);
    }
    float l0 = ba[0], l1 = ba[1], l2 = ba[2], l3 = ba[3];
#pragma unroll
    for (int j = 0; j < 24; ++j) {
        float4 m = S[j];
        float4 w0 = ((const float4*)(Wa + (4 * j + 0) * 4))[0];
        float4 w1 = ((const float4*)(Wa + (4 * j + 1) * 4))[0];
        float4 w2 = ((const float4*)(Wa + (4 * j + 2) * 4))[0];
        float4 w3 = ((const float4*)(Wa + (4 * j + 3) * 4))[0];
        l0 += m.x * w0.x + m.y * w1.x + m.z * w2.x + m.w * w3.x;
        l1 += m.x * w0.y + m.y * w1.y + m.z * w2.y + m.w * w3.y;
        l2 += m.x * w0.z + m.y * w1.z + m.z * w2.z + m.w * w3.z;
        l3 += m.x * w0.w + m.y * w1.w + m.z * w2.w + m.w * w3.w;
    }
    float p0 = __expf(l0), p1 = __expf(l1), p2 = __expf(l2), p3 = __expf(l3);
    float* aggp = aggW + (long)dst * 96;
#pragma unroll 1
    for (int j4 = 0; j4 < 24; ++j4) {
        float4 acc = ((const float4*)bv)[j4];
        const float* Wc = Wv + 4 * j4;
#pragma unroll
        for (int j = 0; j < 24; ++j) {
            float4 m = S[j];
            float4 w0 = ((const float4*)(Wc + (4 * j + 0) * 96))[0];
            float4 w1 = ((const float4*)(Wc + (4 * j + 1) * 96))[0];
            float4 w2 = ((const float4*)(Wc + (4 * j + 2) * 96))[0];
            float4 w3 = ((const float4*)(Wc + (4 * j + 3) * 96))[0];
            acc.x += m.x * w0.x + m.y * w1.x + m.z * w2.x + m.w * w3.x;
            acc.y += m.x * w0.y + m.y * w1.y + m.z * w2.y + m.w * w3.y;
            acc.z += m.x * w0.z + m.y * w1.z + m.z * w2.z + m.w * w3.z;
            acc.w += m.x * w0.w + m.y * w1.w + m.z * w2.w + m.w * w3.w;
        }
        float ph = (j4 < 6) ? p0 : (j4 < 12) ? p1 : (j4 < 18) ? p2 : p3;
        unsafeAtomicAdd(aggp + 4 * j4 + 0, ph * acc.x);
        unsafeAtomicAdd(aggp + 4 * j4 + 1, ph * acc.y);
        unsafeAtomicAdd(aggp + 4 * j4 + 2, ph * acc.z);
        unsafeAtomicAdd(aggp + 4 * j4 + 3, ph * acc.w);
    }
    float* dn = denomW + (long)dst * 4;
    unsafeAtomicAdd(dn + 0, p0);
    unsafeAtomicAdd(dn + 1, p1);
    unsafeAtomicAdd(dn + 2, p2);
    unsafeAtomicAdd(dn + 3, p3);
    unsafeAtomicAdd(cntW + dst, 1.0f);
}

__global__ __launch_bounds__(256, 4)
void node_atm_kernel(const float* __restrict__ x, const float* __restrict__ aggW,
                     const float* __restrict__ denomW, const float* __restrict__ cntW,
                     const float* __restrict__ Wo, const float* __restrict__ bo,
                     float* __restrict__ out, int N)
{
    __shared__ float s_in[161][64];
    int n0 = blockIdx.x * 64;
    int j0 = blockIdx.y * 64;
    for (int p = threadIdx.x; p < 161 * 64; p += 256) {
        int k = p >> 6, nl = p & 63;
        int n = n0 + nl;
        float v = 0.f;
        if (n < N) {
            if (k < 64) v = x[(long)n * 64 + k];
            else if (k < 160) {
                int kk = k - 64;
                float d = denomW[n * 4 + (kk / 24)];
                v = d > 0.f ? aggW[(long)n * 96 + kk] / d : 0.f;
            } else v = cntW[n];
        }
        s_in[k][nl] = v;
    }
    __syncthreads();
    int tj = threadIdx.x & 15;
    int tn = threadIdx.x >> 4;
    float acc[4][4];
#pragma unroll
    for (int i = 0; i < 4; ++i)
#pragma unroll
        for (int c = 0; c < 4; ++c) acc[i][c] = 0.f;
    const float* Wcol = Wo + j0 + tj * 4;
    for (int k = 0; k < 161; ++k) {
        float4 w  = *(const float4*)(Wcol + (long)k * 128);
        float4 iv = *(const float4*)&s_in[k][tn * 4];
        acc[0][0] += iv.x * w.x; acc[0][1] += iv.x * w.y; acc[0][2] += iv.x * w.z; acc[0][3] += iv.x * w.w;
        acc[1][0] += iv.y * w.x; acc[1][1] += iv.y * w.y; acc[1][2] += iv.y * w.z; acc[1][3] += iv.y * w.w;
        acc[2][0] += iv.z * w.x; acc[2][1] += iv.z * w.y; acc[2][2] += iv.z * w.z; acc[2][3] += iv.z * w.w;
        acc[3][0] += iv.w * w.x; acc[3][1] += iv.w * w.y; acc[3][2] += iv.w * w.z; acc[3][3] += iv.w * w.w;
    }
    float4 b = *(const float4*)(bo + j0 + tj * 4);
#pragma unroll
    for (int i = 0; i < 4; ++i) {
        int n = n0 + tn * 4 + i;
        if (n < N) {
            float4 o;
            o.x = lrelu(acc[i][0] + b.x);
            o.y = lrelu(acc[i][1] + b.y);
            o.z = lrelu(acc[i][2] + b.z);
            o.w = lrelu(acc[i][3] + b.w);
            *(float4*)(out + (long)n * 128 + j0 + tj * 4) = o;
        }
    }
}

extern "C" void kernel_launch(void* const* d_in, const int* in_sizes, int n_in,
                              void* d_out, int out_size, void* d_ws, size_t ws_size,
                              hipStream_t stream)
{
    const float* x  = (const float*)d_in[0];
    const float* ea = (const float*)d_in[1];
    const int*   ei = (const int*)d_in[2];
    const float* Wp = (const float*)d_in[3];
    const float* bp = (const float*)d_in[4];
    const float* Wa = (const float*)d_in[5];
    const float* ba = (const float*)d_in[6];
    const float* Wv = (const float*)d_in[7];
    const float* bv = (const float*)d_in[8];
    const float* Wo = (const float*)d_in[9];
    const float* bo = (const float*)d_in[10];
    float* out = (float*)d_out;

    int N = in_sizes[0] / 64;
    int E = in_sizes[2] / 2;

    // vals | U/agg(alias) | cntF | cnti | offs | curs
    size_t need = (size_t)E * 52 * 4 + (size_t)N * 96 * 4 + (size_t)N * 4 * 4;

    if (ws_size >= need) {
        unsigned* vals = (unsigned*)d_ws;
        float* Uagg = (float*)(vals + (long)E * 52);   // U, later overwritten as agg
        float* cntF = Uagg + (long)N * 96;
        int*   cnti = (int*)(cntF + N);
        int*   offs = cnti + N;
        int*   curs = offs + N;

        hipMemsetAsync(cnti, 0, (size_t)N * sizeof(int), stream);
        hist_kernel<<<(E + 255) / 256, 256, 0, stream>>>(ei, cnti, E);
        scan_kernel<<<1, 1024, 0, stream>>>(cnti, offs, curs, N);
        pre_kernel<<<(N + 63) / 64, 256, 0, stream>>>(x, Wp, bp, Uagg, N);
        edge_msg_kernel<<<(E + 255) / 256, 256, 0, stream>>>(
            Uagg, ea, ei, Wp, Wa, ba, vals, curs, E);
        gather_kernel<<<(N + 3) / 4, 256, 0, stream>>>(
            vals, offs, cnti, Wv, bv, Uagg, cntF, N);
        dim3 ng((N + 63) / 64, 2);
        node_kernel<<<ng, 256, 0, stream>>>(x, Uagg, cntF, Wo, bo, out, N);
    } else {
        float* aggW   = (float*)d_ws;
        float* denomW = aggW + (long)N * 96;
        float* cntW   = denomW + (long)N * 4;
        long zn = (long)N * 101;
        int  zb = (int)(((zn + 3) / 4 + 255) / 256);
        zero_kernel<<<zb, 256, 0, stream>>>(aggW, zn);
        edge_atm_kernel<<<(E + 255) / 256, 256, 0, stream>>>(
            x, ea, ei, Wp, bp, Wa, ba, Wv, bv, aggW, denomW, cntW, E);
        dim3 ng((N + 63) / 64, 2);
        node_atm_kernel<<<ng, 256, 0, stream>>>(x, aggW, denomW, cntW, Wo, bo, out, N);
    }
}